// Round 14
// baseline (124.073 us; speedup 1.0000x reference)
//
#include <hip/hip_runtime.h>

// Depthwise Gaussian blur K=121, replicate pad, separable, fp32. FUSED.
// R21 = R20 with the compile fix (wq redefinition: V-phase wq[8] is dead
// after the V loop, so the H macros simply REUSE it -- no alias).
// R20 = R19 + PACKED FP32 (v_pk_fma_f32 probe). At 50.4us the kernel is
// VALU-issue dominated: FMA floor 49K cyc/SIMD of 121K total, 60 TF vs
// ~103 TF scalar ceiling. CDNA3 doubles fp32 via VOP3P v_pk_fma_f32;
// gfx950 has the instruction -- this round measures its rate.
// Pairing: V phase pairs .x/.y (same wk, inputs already adjacent from
// float2 loads -- zero marshaling). H phase pairs (A-span, B-span): same
// wk AND same window idx -> windows stored as interleaved f2 pairs built
// once per group-load (register count unchanged: 64 floats either way).
// Via ext_vector_type(2) + __builtin_elementwise_fma so the backend
// pattern-matches VOP3P. No global-side change (R10-18 lesson).
// R19 learning: SQ_LDS_BANK_CONFLICT is STRUCTURAL (bit-identical 8.6M
// across R13/R16/R19 despite different bank mappings) -- counts inherent
// wave64 multi-cycle service, not fixable stalls. Direction closed.
// Kept: row-parity LDS XOR (R19, small real gain), 3-buffer load-ahead-2
// V phase, scalar pre-normalized weights, paired 32B-stride stores,
// XCD swizzle, launch_bounds(256,6).

#define HH    512
#define WW    512
#define PLANE (512 * 512)
#define NIMG  24
#define ROWF  672                    // 168 16B-units/row, swizzle-bijective

typedef float f2 __attribute__((ext_vector_type(2)));

// ---- pre-kernel: 128 normalized 1-D taps -> d_ws --------------------------
__global__ void wk_prep(const float* __restrict__ sigma,
                        float* __restrict__ wg) {
    const int tid = threadIdx.x;                     // 128 threads, 1 block
    const float s = sigma[0] * 8.0f + 16.0f;
    const float inv2v = 1.0f / (2.0f * s * s);
    float sum = 0.0f;
    #pragma unroll
    for (int k = 0; k <= 120; ++k) {
        const float c = (float)k - 60.0f;
        sum += __expf(-c * c * inv2v);
    }
    float g = 0.0f;
    if (tid < 121) {
        const float c = (float)tid - 60.0f;
        g = __expf(-c * c * inv2v);
    }
    wg[tid] = g / sum;               // taps 121..127 exactly 0
}

// dword offset within an LDS row for padded column `col` (parity-0 form)
__device__ __forceinline__ int swz_off(int col) {
    const int u = col >> 2;
    return ((u ^ ((u >> 3) & 7)) << 2) + (col & 3);
}

// Vertical octet, pipelined: A=X_t, B=X_{t+1}; prefetch C=X_{t+2} first.
// vac[j] = pk_fma(wk, row[base+ki+j], vac[j]) -- .x/.y cols packed.
#define V_OCT_P(A, B, C, KO)                                              \
    { _Pragma("unroll")                                                   \
      for (int ki = 0; ki < 8; ++ki) {                                    \
          int rr = r0 - 44 + (KO) * 8 + ki;                               \
          rr = rr < 0 ? 0 : (rr > HH - 1 ? HH - 1 : rr);                  \
          C[ki] = *(const f2*)&src[(size_t)rr * WW];                      \
      }                                                                   \
      *(float4*)&wq[0] = *(const float4*)&wg[(KO) * 8];                   \
      *(float4*)&wq[4] = *(const float4*)&wg[(KO) * 8 + 4];               \
      _Pragma("unroll")                                                   \
      for (int ki = 0; ki < 8; ++ki) {                                    \
          const float wk = wq[ki];                                        \
          _Pragma("unroll")                                               \
          for (int j = 0; j < 8; ++j) {                                   \
              const int idx = ki + j;                                     \
              const f2 v = (idx < 8) ? A[idx] : B[idx - 8];               \
              vac[j] = __builtin_elementwise_fma(f2{wk, wk}, v, vac[j]);  \
          }                                                               \
      }                                                                   \
    }

// Final octet (KO=15): no prefetch; taps 121..127 are zero.
#define V_OCT_NP(A, B, KO)                                                \
    { *(float4*)&wq[0] = *(const float4*)&wg[(KO) * 8];                   \
      *(float4*)&wq[4] = *(const float4*)&wg[(KO) * 8 + 4];               \
      _Pragma("unroll")                                                   \
      for (int ki = 0; ki < 8; ++ki) {                                    \
          const float wk = wq[ki];                                        \
          _Pragma("unroll")                                               \
          for (int j = 0; j < 8; ++j) {                                   \
              const int idx = ki + j;                                     \
              const f2 v = (idx < 8) ? A[idx] : B[idx - 8];               \
              vac[j] = __builtin_elementwise_fma(f2{wk, wk}, v, vac[j]);  \
          }                                                               \
      }                                                                   \
    }

// Load group G (span A) and G+32 (span B), interleaved into f2 pairs
// (.x = A-span value, .y = B-span value). parx4 = row-parity unit flip.
#define LOADG2P(DAB, G)                                                   \
    { const int u_  = 2 * (G);                                            \
      const int o1_ = (((u_ ^ ((u_ >> 3) & 7)) << 2)) ^ parx4;            \
      const int o2_ = o1_ ^ 4;                                            \
      const float4 qa0 = *(const float4*)(bs + o1_);                      \
      const float4 qa1 = *(const float4*)(bs + o2_);                      \
      const float4 qb0 = *(const float4*)(bs + o1_ + 256);                \
      const float4 qb1 = *(const float4*)(bs + o2_ + 256);                \
      DAB[0] = f2{qa0.x, qb0.x}; DAB[1] = f2{qa0.y, qb0.y};               \
      DAB[2] = f2{qa0.z, qb0.z}; DAB[3] = f2{qa0.w, qb0.w};               \
      DAB[4] = f2{qa1.x, qb1.x}; DAB[5] = f2{qa1.y, qb1.y};               \
      DAB[6] = f2{qa1.z, qb1.z}; DAB[7] = f2{qa1.w, qb1.w}; }

// One octet, both spans packed: acc2[j] = pk_fma(wk, win[idx], acc2[j])
#define H_OCT2P(A0, A1, A2, A3, KO)                                       \
    { LOADG2P(A3, L + (KO) + 3)                                           \
      *(float4*)&wq[0] = *(const float4*)&wg[(KO) * 8];                   \
      *(float4*)&wq[4] = *(const float4*)&wg[(KO) * 8 + 4];               \
      _Pragma("unroll")                                                   \
      for (int ki = 0; ki < 8; ++ki) {                                    \
          const float wk = wq[ki];                                        \
          _Pragma("unroll")                                               \
          for (int j = 0; j < 8; ++j) {                                   \
              const int idx = ki + j;                                     \
              const f2 v = (idx < 8) ? A0[idx]                            \
                         : (idx < 16) ? A1[idx - 8] : A2[idx - 16];       \
              acc2[j] = __builtin_elementwise_fma(f2{wk, wk}, v, acc2[j]);\
          }                                                               \
      }                                                                   \
    }

__global__ __launch_bounds__(256, 6) void blur_fused(
        const float* __restrict__ x, const float* __restrict__ wg,
        float* __restrict__ out) {
    __shared__ float sm[8 * ROWF];                   // 21504 B
    const int tid = threadIdx.x;

    // XCD swizzle: linear id -> contiguous 192-tile span per XCD (%8 rr).
    const int lid   = blockIdx.x + gridDim.x * blockIdx.y;   // 0..1535
    const int tile  = (lid & 7) * 192 + (lid >> 3);
    const int r0    = (tile & 63) * 8;               // output rows r0..r0+7
    const int plane = tile >> 6;

    const int c0 = tid * 2;                          // this thread's 2 cols
    const float* __restrict__ src = x + (size_t)plane * PLANE + c0;

    // ---- vertical: 8 rows x 2 cols, 3-buffer load-ahead-by-2 pipeline ----
    f2 w0[8], w1[8], w2[8], vac[8];
    float wq[8];                                     // reused by H phase too
    #pragma unroll
    for (int m = 0; m < 8; ++m) {                    // X_0: rows r0-60..r0-53
        int rr = r0 - 60 + m;
        rr = rr < 0 ? 0 : rr;
        w0[m] = *(const f2*)&src[(size_t)rr * WW];
    }
    #pragma unroll
    for (int m = 0; m < 8; ++m) {                    // X_1: rows r0-52..r0-45
        int rr = r0 - 52 + m;
        rr = rr < 0 ? 0 : rr;
        w1[m] = *(const f2*)&src[(size_t)rr * WW];
    }
    #pragma unroll
    for (int j = 0; j < 8; ++j) vac[j] = f2{0.f, 0.f};

    #pragma unroll 1
    for (int ko = 0; ko < 15; ko += 3) {             // octets 0..14, period-3
        V_OCT_P(w0, w1, w2, ko)
        V_OCT_P(w1, w2, w0, ko + 1)
        V_OCT_P(w2, w0, w1, ko + 2)
    }
    V_OCT_NP(w0, w1, 15)                             // octet 15, no prefetch

    // write intermediate at halo offset +60; row-parity XOR (^4 dw if odd)
    {
        const int off = swz_off(c0 + 60);            // parity-0 offset
        #pragma unroll
        for (int j = 0; j < 8; ++j)
            *(f2*)&sm[j * ROWF + (off ^ ((j & 1) << 2))] = vac[j];
    }
    __syncthreads();

    // ---- halo: idx 0..59 <- 60; 572..647 <- 571; zero 648..655 -----------
    if (tid < 36) {
        const int p = (tid < 15) ? tid * 4
                    : (tid < 34) ? 572 + (tid - 15) * 4
                                 : 648 + (tid - 34) * 4;
        const int u    = p >> 2;
        const int off0 = (u ^ ((u >> 3) & 7)) << 2;  // 16B-aligned, parity 0
        const int sof0 = (tid < 15) ? swz_off(60) : swz_off(571);
        #pragma unroll
        for (int r8 = 0; r8 < 8; ++r8) {
            const int pp = (r8 & 1) << 2;
            const float v = (tid < 34) ? sm[r8 * ROWF + (sof0 ^ pp)] : 0.0f;
            *(float4*)&sm[r8 * ROWF + (off0 ^ pp)] = make_float4(v, v, v, v);
        }
    }
    __syncthreads();

    // ---- horizontal: two 8-col spans per lane, packed A/B windows --------
    const int r = tid >> 5;                          // 0..7
    const int L = tid & 31;                          // span A cols 8L.., B +256
    const int parx4 = (r & 1) << 2;                  // row-parity unit flip
    const float* __restrict__ bs = sm + r * ROWF;

    f2 a0[8], a1[8], a2[8], a3[8];
    f2 acc2[8];
    #pragma unroll
    for (int j = 0; j < 8; ++j) acc2[j] = f2{0.f, 0.f};

    LOADG2P(a0, L)
    LOADG2P(a1, L + 1)
    LOADG2P(a2, L + 2)

    #pragma unroll 1
    for (int ko = 0; ko < 16; ko += 4) {
        H_OCT2P(a0, a1, a2, a3, ko)
        H_OCT2P(a1, a2, a3, a0, ko + 1)
        H_OCT2P(a2, a3, a0, a1, ko + 2)
        H_OCT2P(a3, a0, a1, a2, ko + 3)
    }

    float* __restrict__ dst = out + (size_t)plane * PLANE
                                  + (size_t)(r0 + r) * WW + L * 8;
    *(float4*)(dst)       = make_float4(acc2[0].x, acc2[1].x,
                                        acc2[2].x, acc2[3].x);
    *(float4*)(dst + 4)   = make_float4(acc2[4].x, acc2[5].x,
                                        acc2[6].x, acc2[7].x);
    *(float4*)(dst + 256) = make_float4(acc2[0].y, acc2[1].y,
                                        acc2[2].y, acc2[3].y);
    *(float4*)(dst + 260) = make_float4(acc2[4].y, acc2[5].y,
                                        acc2[6].y, acc2[7].y);
}

extern "C" void kernel_launch(void* const* d_in, const int* in_sizes, int n_in,
                              void* d_out, int out_size, void* d_ws, size_t ws_size,
                              hipStream_t stream) {
    const float* x     = (const float*)d_in[0];
    const float* sigma = (const float*)d_in[1];
    float* out = (float*)d_out;
    float* wg  = (float*)d_ws;                       // 512 B of workspace
    wk_prep<<<dim3(1), dim3(128), 0, stream>>>(sigma, wg);
    blur_fused<<<dim3(HH / 8, NIMG), dim3(256), 0, stream>>>(x, wg, out);
}

// Round 15
// 114.723 us; speedup vs baseline: 1.0815x; 1.0815x over previous
//
#include <hip/hip_runtime.h>

// Depthwise Gaussian blur K=121, replicate pad, separable, fp32. FUSED.
// R22 = REVERT to R19 verbatim -- the best verified kernel (50.4us/dispatch,
// clean traffic FETCH 12.36 / WRITE 24.6 MB = 1.0x logical).
// Closed directions (counter evidence):
//  - pk fp32 (R21): VALU time identical (28.0us) -> VOP3P fp32 not
//    double-rate / not emitted; also flipped traffic dirty.
//  - conflict swizzles (R7/R8/R19): SQ_LDS_BANK_CONFLICT structural
//    (bit-identical 8.6M across different bank mappings).
//  - V-latency pipelining (R16): null at 24 waves/CU.
//  - taller tiles (R14/R15): LDS->occupancy cliff, 80us + dirty traffic.
//  - 16-col H spans (R10/12/17/18): LDS win real but ALWAYS traffic-dirty
//    regardless of store geometry / lane order.
// Empirical rule (7/7 rounds): any structural deviation from this exact
// kernel shape flips HBM WRITE 2.2-13x. Keep: row-parity LDS XOR,
// 3-buffer load-ahead-2 V phase, scalar pre-normalized weights from d_ws,
// paired 32B-stride stores, XCD swizzle, launch_bounds(256,6).

#define HH    512
#define WW    512
#define PLANE (512 * 512)
#define NIMG  24
#define ROWF  672                    // 168 16B-units/row, swizzle-bijective

// ---- pre-kernel: 128 normalized 1-D taps -> d_ws --------------------------
__global__ void wk_prep(const float* __restrict__ sigma,
                        float* __restrict__ wg) {
    const int tid = threadIdx.x;                     // 128 threads, 1 block
    const float s = sigma[0] * 8.0f + 16.0f;
    const float inv2v = 1.0f / (2.0f * s * s);
    float sum = 0.0f;
    #pragma unroll
    for (int k = 0; k <= 120; ++k) {
        const float c = (float)k - 60.0f;
        sum += __expf(-c * c * inv2v);
    }
    float g = 0.0f;
    if (tid < 121) {
        const float c = (float)tid - 60.0f;
        g = __expf(-c * c * inv2v);
    }
    wg[tid] = g / sum;               // taps 121..127 exactly 0
}

// dword offset within an LDS row for padded column `col` (parity-0 form)
__device__ __forceinline__ int swz_off(int col) {
    const int u = col >> 2;
    return ((u ^ ((u >> 3) & 7)) << 2) + (col & 3);
}

// Vertical octet, pipelined: A=X_t (rows base..), B=X_{t+1}; prefetch
// C=X_{t+2} (rows base+16.., clamped) issued BEFORE the FMAs.
#define V_OCT_P(A, B, C, KO)                                              \
    { _Pragma("unroll")                                                   \
      for (int ki = 0; ki < 8; ++ki) {                                    \
          int rr = r0 - 44 + (KO) * 8 + ki;                               \
          rr = rr < 0 ? 0 : (rr > HH - 1 ? HH - 1 : rr);                  \
          C[ki] = *(const float2*)&src[(size_t)rr * WW];                  \
      }                                                                   \
      *(float4*)&wq[0] = *(const float4*)&wg[(KO) * 8];                   \
      *(float4*)&wq[4] = *(const float4*)&wg[(KO) * 8 + 4];               \
      _Pragma("unroll")                                                   \
      for (int ki = 0; ki < 8; ++ki) {                                    \
          const float wk = wq[ki];                                        \
          _Pragma("unroll")                                               \
          for (int j = 0; j < 8; ++j) {                                   \
              const int idx = ki + j;                                     \
              const float2 v = (idx < 8) ? A[idx] : B[idx - 8];           \
              vac[j].x += wk * v.x; vac[j].y += wk * v.y;                 \
          }                                                               \
      }                                                                   \
    }

// Final octet (KO=15): no prefetch; taps 121..127 are zero.
#define V_OCT_NP(A, B, KO)                                                \
    { *(float4*)&wq[0] = *(const float4*)&wg[(KO) * 8];                   \
      *(float4*)&wq[4] = *(const float4*)&wg[(KO) * 8 + 4];               \
      _Pragma("unroll")                                                   \
      for (int ki = 0; ki < 8; ++ki) {                                    \
          const float wk = wq[ki];                                        \
          _Pragma("unroll")                                               \
          for (int j = 0; j < 8; ++j) {                                   \
              const int idx = ki + j;                                     \
              const float2 v = (idx < 8) ? A[idx] : B[idx - 8];           \
              vac[j].x += wk * v.x; vac[j].y += wk * v.y;                 \
          }                                                               \
      }                                                                   \
    }

// Load group G (span A) and G+32 (span B). parx4 = (row&1)<<2 flips unit
// parity: lanes of row r read even phys units, row r+1 odd -> 32 banks.
#define LOADG2(DA, DB, G)                                                 \
    { const int u_  = 2 * (G);                                            \
      const int o1_ = (((u_ ^ ((u_ >> 3) & 7)) << 2)) ^ parx4;            \
      const int o2_ = o1_ ^ 4;                                            \
      *(float4*)&DA[0] = *(const float4*)(bs + o1_);                      \
      *(float4*)&DA[4] = *(const float4*)(bs + o2_);                      \
      *(float4*)&DB[0] = *(const float4*)(bs + o1_ + 256);                \
      *(float4*)&DB[4] = *(const float4*)(bs + o2_ + 256); }

// One octet, TWO 8-col spans (A: groups L+.., B: groups L+32+..)
#define H_OCT2(A0, A1, A2, A3, B0, B1, B2, B3, KO)                        \
    { LOADG2(A3, B3, L + (KO) + 3)                                        \
      *(float4*)&wq[0] = *(const float4*)&wg[(KO) * 8];                   \
      *(float4*)&wq[4] = *(const float4*)&wg[(KO) * 8 + 4];               \
      _Pragma("unroll")                                                   \
      for (int ki = 0; ki < 8; ++ki) {                                    \
          const float wk = wq[ki];                                        \
          _Pragma("unroll")                                               \
          for (int j = 0; j < 8; ++j) {                                   \
              const int idx = ki + j;                                     \
              const float vA = (idx < 8) ? A0[idx]                        \
                             : (idx < 16) ? A1[idx - 8] : A2[idx - 16];   \
              const float vB = (idx < 8) ? B0[idx]                        \
                             : (idx < 16) ? B1[idx - 8] : B2[idx - 16];   \
              accA[j] += wk * vA;                                         \
              accB[j] += wk * vB;                                         \
          }                                                               \
      }                                                                   \
    }

__global__ __launch_bounds__(256, 6) void blur_fused(
        const float* __restrict__ x, const float* __restrict__ wg,
        float* __restrict__ out) {
    __shared__ float sm[8 * ROWF];                   // 21504 B
    const int tid = threadIdx.x;

    // XCD swizzle: linear id -> contiguous 192-tile span per XCD (%8 rr).
    const int lid   = blockIdx.x + gridDim.x * blockIdx.y;   // 0..1535
    const int tile  = (lid & 7) * 192 + (lid >> 3);
    const int r0    = (tile & 63) * 8;               // output rows r0..r0+7
    const int plane = tile >> 6;

    const int c0 = tid * 2;                          // this thread's 2 cols
    const float* __restrict__ src = x + (size_t)plane * PLANE + c0;

    // ---- vertical: 8 rows x 2 cols, 3-buffer load-ahead-by-2 pipeline ----
    float2 w0[8], w1[8], w2[8], vac[8];
    float  wq[8];
    #pragma unroll
    for (int m = 0; m < 8; ++m) {                    // X_0: rows r0-60..r0-53
        int rr = r0 - 60 + m;
        rr = rr < 0 ? 0 : rr;
        w0[m] = *(const float2*)&src[(size_t)rr * WW];
    }
    #pragma unroll
    for (int m = 0; m < 8; ++m) {                    // X_1: rows r0-52..r0-45
        int rr = r0 - 52 + m;
        rr = rr < 0 ? 0 : rr;
        w1[m] = *(const float2*)&src[(size_t)rr * WW];
    }
    #pragma unroll
    for (int j = 0; j < 8; ++j) vac[j] = make_float2(0.f, 0.f);

    #pragma unroll 1
    for (int ko = 0; ko < 15; ko += 3) {             // octets 0..14, period-3
        V_OCT_P(w0, w1, w2, ko)
        V_OCT_P(w1, w2, w0, ko + 1)
        V_OCT_P(w2, w0, w1, ko + 2)
    }
    V_OCT_NP(w0, w1, 15)                             // octet 15, no prefetch

    // write intermediate at halo offset +60; row-parity XOR (^4 dw if odd)
    {
        const int off = swz_off(c0 + 60);            // parity-0 offset
        #pragma unroll
        for (int j = 0; j < 8; ++j)
            *(float2*)&sm[j * ROWF + (off ^ ((j & 1) << 2))] = vac[j];
    }
    __syncthreads();

    // ---- halo: idx 0..59 <- 60; 572..647 <- 571; zero 648..655 -----------
    if (tid < 36) {
        const int p = (tid < 15) ? tid * 4
                    : (tid < 34) ? 572 + (tid - 15) * 4
                                 : 648 + (tid - 34) * 4;
        const int u    = p >> 2;
        const int off0 = (u ^ ((u >> 3) & 7)) << 2;  // 16B-aligned, parity 0
        const int sof0 = (tid < 15) ? swz_off(60) : swz_off(571);
        #pragma unroll
        for (int r8 = 0; r8 < 8; ++r8) {
            const int pp = (r8 & 1) << 2;
            const float v = (tid < 34) ? sm[r8 * ROWF + (sof0 ^ pp)] : 0.0f;
            *(float4*)&sm[r8 * ROWF + (off0 ^ pp)] = make_float4(v, v, v, v);
        }
    }
    __syncthreads();

    // ---- horizontal: two 8-col spans per lane, rotating 4-octet windows --
    const int r = tid >> 5;                          // 0..7
    const int L = tid & 31;                          // span A cols 8L.., B +256
    const int parx4 = (r & 1) << 2;                  // row-parity unit flip
    const float* __restrict__ bs = sm + r * ROWF;

    float a0[8], a1[8], a2[8], a3[8];
    float b0[8], b1[8], b2[8], b3[8];
    float accA[8], accB[8];
    #pragma unroll
    for (int j = 0; j < 8; ++j) { accA[j] = 0.0f; accB[j] = 0.0f; }

    LOADG2(a0, b0, L)
    LOADG2(a1, b1, L + 1)
    LOADG2(a2, b2, L + 2)

    #pragma unroll 1
    for (int ko = 0; ko < 16; ko += 4) {
        H_OCT2(a0, a1, a2, a3, b0, b1, b2, b3, ko)
        H_OCT2(a1, a2, a3, a0, b1, b2, b3, b0, ko + 1)
        H_OCT2(a2, a3, a0, a1, b2, b3, b0, b1, ko + 2)
        H_OCT2(a3, a0, a1, a2, b3, b0, b1, b2, ko + 3)
    }

    float* __restrict__ dst = out + (size_t)plane * PLANE
                                  + (size_t)(r0 + r) * WW + L * 8;
    *(float4*)(dst)       = make_float4(accA[0], accA[1], accA[2], accA[3]);
    *(float4*)(dst + 4)   = make_float4(accA[4], accA[5], accA[6], accA[7]);
    *(float4*)(dst + 256) = make_float4(accB[0], accB[1], accB[2], accB[3]);
    *(float4*)(dst + 260) = make_float4(accB[4], accB[5], accB[6], accB[7]);
}

extern "C" void kernel_launch(void* const* d_in, const int* in_sizes, int n_in,
                              void* d_out, int out_size, void* d_ws, size_t ws_size,
                              hipStream_t stream) {
    const float* x     = (const float*)d_in[0];
    const float* sigma = (const float*)d_in[1];
    float* out = (float*)d_out;
    float* wg  = (float*)d_ws;                       // 512 B of workspace
    wk_prep<<<dim3(1), dim3(128), 0, stream>>>(sigma, wg);
    blur_fused<<<dim3(HH / 8, NIMG), dim3(256), 0, stream>>>(x, wg, out);
}